// Round 4
// baseline (787.867 us; speedup 1.0000x reference)
//
#include <hip/hip_runtime.h>

#define RL(x) __builtin_amdgcn_readfirstlane(x)

// ---------------- weight prep: transpose conv2/conv3 weights to lane-coalesced layouts ----
// wt2[((ic*4+q)*64+oc)*4+c] = w2[oc][ic][q*4+c]           (32*64*16  = 32768)
// wt3[((ic*3+q)*64+oc)*4+c] = (q*4+c<9) ? w3[oc][ic][q*4+c] : 0   (64*64*12 = 49152)
__global__ __launch_bounds__(256) void wprep_k(const float* __restrict__ w2,
                                               const float* __restrict__ w3,
                                               float* __restrict__ wt2,
                                               float* __restrict__ wt3) {
  int i = blockIdx.x * 256 + threadIdx.x;
  if (i < 32768) {
    int oc = i >> 9, rem = i & 511;          // rem = ic*16 + t
    int ic = rem >> 4, t = rem & 15;
    wt2[((ic * 4 + (t >> 2)) * 64 + oc) * 4 + (t & 3)] = w2[i];
  }
  if (i < 49152) {
    int oc = i / 768, rem = i - oc * 768;    // rem = ic*12 + t
    int ic = rem / 12, t = rem - ic * 12;
    float v = (t < 9) ? w3[oc * 576 + ic * 9 + t] : 0.f;
    wt3[((ic * 3 + (t >> 2)) * 64 + oc) * 4 + (t & 3)] = v;
  }
}

// ---------------- conv1: x[1024,4,84,84] -> c1[1024,32,20,20], k=8, s=4 ----------------
// Pixels on lanes, weights from LDS broadcast (unchanged from R2).
__global__ __launch_bounds__(256, 2) void conv1_k(const float* __restrict__ x,
                                                  const float* __restrict__ w,    // [32,4,8,8]
                                                  const float* __restrict__ bias,
                                                  float* __restrict__ out) {
  __shared__ float wl[8192];
  const int b    = blockIdx.x;
  const int tid  = threadIdx.x;
  const int lane = tid & 63;
  const int g    = RL(tid >> 6);

#pragma unroll
  for (int i = 0; i < 32; ++i) {
    int idx = tid + i * 256;
    int oc = idx >> 8, rem = idx & 255;
    wl[(rem >> 3) * 256 + oc * 8 + (rem & 7)] = w[idx];
  }
  __syncthreads();

  int pv[7], ib[7];
#pragma unroll
  for (int s = 0; s < 7; ++s) {
    int p = lane + 64 * s;
    pv[s] = (p < 400);
    if (p > 399) p = 399;
    int py = p / 20, px = p - py * 20;
    ib[s] = py * 336 + px * 4;
  }

  float acc[7][8];
#pragma unroll
  for (int s = 0; s < 7; ++s)
#pragma unroll
    for (int j = 0; j < 8; ++j) acc[s][j] = 0.f;

  const float* xb = x + b * 28224;
#pragma unroll 1
  for (int ic = 0; ic < 4; ++ic) {
#pragma unroll 1
    for (int ky = 0; ky < 8; ++ky) {
      const float* wp = &wl[(ic * 8 + ky) * 256 + g * 64];
      float wr[8][8];
#pragma unroll
      for (int j = 0; j < 8; ++j) {
        float4 w0 = *(const float4*)(wp + j * 8);
        float4 w1 = *(const float4*)(wp + j * 8 + 4);
        wr[j][0]=w0.x; wr[j][1]=w0.y; wr[j][2]=w0.z; wr[j][3]=w0.w;
        wr[j][4]=w1.x; wr[j][5]=w1.y; wr[j][6]=w1.z; wr[j][7]=w1.w;
      }
      const float* rp = xb + ic * 7056 + ky * 84;
#pragma unroll
      for (int s = 0; s < 7; ++s) {
        float4 a = *(const float4*)(rp + ib[s]);
        float4 c = *(const float4*)(rp + ib[s] + 4);
        float in8[8] = {a.x, a.y, a.z, a.w, c.x, c.y, c.z, c.w};
#pragma unroll
        for (int j = 0; j < 8; ++j)
#pragma unroll
          for (int kx = 0; kx < 8; ++kx)
            acc[s][j] = fmaf(in8[kx], wr[j][kx], acc[s][j]);
      }
    }
  }

  const float inv256 = 1.0f / 256.0f;
#pragma unroll
  for (int j = 0; j < 8; ++j) {
    float bj = bias[g * 8 + j];
    float* op = out + (b * 32 + g * 8 + j) * 400;
#pragma unroll
    for (int s = 0; s < 7; ++s) {
      if (pv[s]) {
        float v = acc[s][j] * inv256 + bj;
        op[lane + 64 * s] = v > 0.f ? v : 0.f;
      }
    }
  }
}

// ---------------- conv2: c1[1024,32,20,20] -> c2[1024,64,9,9], k=4, s=2 ----------------
// Block = 1 image (5 waves); lanes = 64 oc; wave w owns output rows {2w,2w+1}
// (wave 4: row 8). Whole image staged to LDS (51.2KB); rows read as uniform
// ds_read_b128 broadcasts. Weights lane-coalesced from pre-transposed wt2.
// 6-row scheme: input row r feeds acc0 via ky=r (r<4) and acc1 via ky=r-2 (r>=2).
__global__ __launch_bounds__(320, 2) void conv2_k(const float* __restrict__ in,
                                                  const float* __restrict__ wt,   // [ic][q][oc][4]
                                                  const float* __restrict__ bias,
                                                  float* __restrict__ out) {
  __shared__ float img[12800];
  const int b   = blockIdx.x;
  const int tid = threadIdx.x;
  const int j   = tid & 63;
  const int wv  = RL(tid >> 6);        // 0..4
  const int py0 = 2 * wv;
  const int nr  = (wv == 4) ? 1 : 2;
  const int rmax = (wv == 4) ? 4 : 6;

  {
    const float4* src = (const float4*)(in + b * 12800);
    float4* dst = (float4*)img;
#pragma unroll
    for (int z = 0; z < 10; ++z) dst[tid + z * 320] = src[tid + z * 320];
  }
  __syncthreads();

  float acc[2][9];
#pragma unroll
  for (int rr = 0; rr < 2; ++rr)
#pragma unroll
    for (int px = 0; px < 9; ++px) acc[rr][px] = 0.f;

  const float* rbase = img + wv * 80;  // input row 4wv
  const float4* wt4  = (const float4*)wt;

#pragma unroll 1
  for (int ic2 = 0; ic2 < 16; ++ic2) {
#pragma unroll
    for (int e = 0; e < 2; ++e) {
      const int ic = ic2 * 2 + e;
      float wk[16];
#pragma unroll
      for (int q = 0; q < 4; ++q) {
        float4 t = wt4[(ic * 4 + q) * 64 + j];
        wk[q*4]=t.x; wk[q*4+1]=t.y; wk[q*4+2]=t.z; wk[q*4+3]=t.w;
      }
      const float* icp = rbase + ic * 400;
#pragma unroll
      for (int r = 0; r < 6; ++r) {
        if (r < rmax) {
          float rw[20];
#pragma unroll
          for (int q = 0; q < 5; ++q) {
            float4 t = *(const float4*)(icp + r * 20 + q * 4);
            rw[q*4]=t.x; rw[q*4+1]=t.y; rw[q*4+2]=t.z; rw[q*4+3]=t.w;
          }
          if (r < 4) {
#pragma unroll
            for (int px = 0; px < 9; ++px)
#pragma unroll
              for (int kx = 0; kx < 4; ++kx)
                acc[0][px] = fmaf(rw[2*px+kx], wk[r*4+kx], acc[0][px]);
          }
          if (r >= 2 && nr == 2) {
#pragma unroll
            for (int px = 0; px < 9; ++px)
#pragma unroll
              for (int kx = 0; kx < 4; ++kx)
                acc[1][px] = fmaf(rw[2*px+kx], wk[(r-2)*4+kx], acc[1][px]);
          }
        }
      }
    }
  }

  const float bj = bias[j];
#pragma unroll
  for (int rr = 0; rr < 2; ++rr) {
    if (rr < nr) {
      float* op = out + (b * 64 + j) * 81 + (py0 + rr) * 9;
#pragma unroll
      for (int px = 0; px < 9; ++px) {
        float v = acc[rr][px] + bj;
        op[px] = v > 0.f ? v : 0.f;
      }
    }
  }
}

// ---------------- conv3: c2[1024,64,9,9] -> c3[1024,64,7,7], k=3, s=1 ----------------
// Block = 1 image (4 waves); lanes = 64 oc; wave (rotated by b) owns rows
// {2w,2w+1} (wave 3: row 6). Image staged to LDS padded [ic][row][12] (rows
// 16B-aligned, 27.6KB); weights lane-coalesced from zero-padded wt3.
__global__ __launch_bounds__(256, 2) void conv3_k(const float* __restrict__ in,
                                                  const float* __restrict__ wt,   // [ic][q][oc][4]
                                                  const float* __restrict__ bias,
                                                  float* __restrict__ out) {
  __shared__ float img[6912];   // 64 * 9 * 12
  const int b   = blockIdx.x;
  const int tid = threadIdx.x;
  const int j   = tid & 63;
  const int wv  = (RL(tid >> 6) + b) & 3;
  const int py0 = 2 * wv;
  const int nr  = (wv == 3) ? 1 : 2;
  const int nrow = nr + 2;             // 4 rows (or 3 for wave 3)

  {
    const float4* src = (const float4*)(in + b * 5184);
    for (int i = tid; i < 1296; i += 256) {
      float4 v = src[i];
      int p = i * 4;
      float vv[4] = {v.x, v.y, v.z, v.w};
#pragma unroll
      for (int c = 0; c < 4; ++c) {
        int q = p + c;
        int ic = q / 81, rem = q - ic * 81;
        int r = rem / 9, cc = rem - r * 9;
        img[ic * 108 + r * 12 + cc] = vv[c];
      }
    }
  }
  __syncthreads();

  float acc[2][7];
#pragma unroll
  for (int rr = 0; rr < 2; ++rr)
#pragma unroll
    for (int px = 0; px < 7; ++px) acc[rr][px] = 0.f;

  const float4* wt4 = (const float4*)wt;

#pragma unroll 1
  for (int ic2 = 0; ic2 < 32; ++ic2) {
#pragma unroll
    for (int e = 0; e < 2; ++e) {
      const int ic = ic2 * 2 + e;
      float wk[12];
#pragma unroll
      for (int q = 0; q < 3; ++q) {
        float4 t = wt4[(ic * 3 + q) * 64 + j];
        wk[q*4]=t.x; wk[q*4+1]=t.y; wk[q*4+2]=t.z; wk[q*4+3]=t.w;
      }
      float rows[4][9];
      const float* base = img + ic * 108 + py0 * 12;
#pragma unroll
      for (int rr = 0; rr < 4; ++rr) {
        if (rr < nrow) {
          const float* rp = base + rr * 12;     // 48B-aligned
          float4 a = *(const float4*)rp;
          float4 c = *(const float4*)(rp + 4);
          rows[rr][0]=a.x; rows[rr][1]=a.y; rows[rr][2]=a.z; rows[rr][3]=a.w;
          rows[rr][4]=c.x; rows[rr][5]=c.y; rows[rr][6]=c.z; rows[rr][7]=c.w;
          rows[rr][8]=rp[8];
        }
      }
#pragma unroll
      for (int ky = 0; ky < 3; ++ky) {
#pragma unroll
        for (int rr = 0; rr < 2; ++rr) {
          if (rr < nr) {
#pragma unroll
            for (int px = 0; px < 7; ++px)
#pragma unroll
              for (int kx = 0; kx < 3; ++kx)
                acc[rr][px] = fmaf(rows[ky+rr][px+kx], wk[ky*3+kx], acc[rr][px]);
          }
        }
      }
    }
  }

  const float bj = bias[j];
#pragma unroll
  for (int rr = 0; rr < 2; ++rr) {
    if (rr < nr) {
      float* op = out + b * 3136 + j * 49 + (py0 + rr) * 7;
#pragma unroll
      for (int px = 0; px < 7; ++px) {
        float v = acc[rr][px] + bj;
        op[px] = v > 0.f ? v : 0.f;
      }
    }
  }
}

// ---------------- fc1a: c3[1024][3136] @ fw1[3136][256] -> partial[8][1024][256] ----------------
__global__ __launch_bounds__(256) void fc1a_k(const float* __restrict__ a,
                                              const float* __restrict__ w,
                                              float* __restrict__ part) {
  __shared__ float al[56][20];
  const int b0  = blockIdx.x * 16;
  const int k0  = blockIdx.y * 392;
  const int tid = threadIdx.x;
  const int jj  = tid & 63;
  const int ib  = RL(tid >> 6);

  float acc[4][4];
#pragma unroll
  for (int r = 0; r < 4; ++r)
#pragma unroll
    for (int c = 0; c < 4; ++c) acc[r][c] = 0.f;

#pragma unroll 1
  for (int t = 0; t < 7; ++t) {
    __syncthreads();
#pragma unroll
    for (int z = 0; z < 4; ++z) {
      int idx = tid + z * 256;
      if (idx < 896) {
        int i = idx / 56, kk = idx - i * 56;
        al[kk][i] = a[(b0 + i) * 3136 + k0 + t * 56 + kk];
      }
    }
    __syncthreads();
#pragma unroll 2
    for (int kk = 0; kk < 56; ++kk) {
      float4 wv4 = *(const float4*)&w[(k0 + t * 56 + kk) * 256 + jj * 4];
      float4 av  = *(const float4*)&al[kk][ib * 4];
      float avr[4] = {av.x, av.y, av.z, av.w};
#pragma unroll
      for (int r = 0; r < 4; ++r) {
        acc[r][0] = fmaf(avr[r], wv4.x, acc[r][0]);
        acc[r][1] = fmaf(avr[r], wv4.y, acc[r][1]);
        acc[r][2] = fmaf(avr[r], wv4.z, acc[r][2]);
        acc[r][3] = fmaf(avr[r], wv4.w, acc[r][3]);
      }
    }
  }
#pragma unroll
  for (int r = 0; r < 4; ++r) {
    float4 v = {acc[r][0], acc[r][1], acc[r][2], acc[r][3]};
    *(float4*)&part[(blockIdx.y * 1024 + b0 + ib * 4 + r) * 256 + jj * 4] = v;
  }
}

// ---------------- fc1b: reduce 8 partials + bias + relu -> h[1024][256] ----------------
__global__ __launch_bounds__(256) void fc1b_k(const float* __restrict__ part,
                                              const float* __restrict__ bias,
                                              float* __restrict__ h) {
  int idx = blockIdx.x * 256 + threadIdx.x;
  int j = idx & 255;
  float s = bias[j];
#pragma unroll
  for (int c = 0; c < 8; ++c) s += part[c * 262144 + idx];
  h[idx] = s > 0.f ? s : 0.f;
}

// ---------------- fc2 + softmax + dist/res ----------------
__global__ __launch_bounds__(256) void fc2_k(const float* __restrict__ h,
                                             const float* __restrict__ w,   // [256][51]
                                             const float* __restrict__ bias,
                                             const float* __restrict__ z,
                                             float* __restrict__ dist,      // [1024][6][51]
                                             float* __restrict__ res) {     // [1024][6]
  const int tid = threadIdx.x;
  const int j   = tid & 63;
  const int b   = blockIdx.x * 4 + RL(tid >> 6);
  const float* hb = h + b * 256;
  const int jc = j < 51 ? j : 50;
  float acc = bias[jc];
#pragma unroll 4
  for (int k = 0; k < 256; ++k)
    acc = fmaf(hb[k], w[k * 51 + jc], acc);
  float logit = (j < 51) ? acc : -1e30f;
  float m = logit;
#pragma unroll
  for (int o = 32; o > 0; o >>= 1) m = fmaxf(m, __shfl_xor(m, o, 64));
  float e = (j < 51) ? __expf(logit - m) : 0.f;
  float ssum = e;
#pragma unroll
  for (int o = 32; o > 0; o >>= 1) ssum += __shfl_xor(ssum, o, 64);
  float p = e / ssum;
  float zv = (j < 51) ? z[jc] : 0.f;
  float rz = p * zv;
#pragma unroll
  for (int o = 32; o > 0; o >>= 1) rz += __shfl_xor(rz, o, 64);
  if (j < 51) {
    float* db = dist + b * 6 * 51 + j;
#pragma unroll
    for (int n = 0; n < 6; ++n) db[n * 51] = p;
  }
  if (j < 6) res[b * 6 + j] = rz;
}

extern "C" void kernel_launch(void* const* d_in, const int* in_sizes, int n_in,
                              void* d_out, int out_size, void* d_ws, size_t ws_size,
                              hipStream_t stream) {
  const float* x   = (const float*)d_in[0];
  const float* cw1 = (const float*)d_in[1];
  const float* cb1 = (const float*)d_in[2];
  const float* cw2 = (const float*)d_in[3];
  const float* cb2 = (const float*)d_in[4];
  const float* cw3 = (const float*)d_in[5];
  const float* cb3 = (const float*)d_in[6];
  const float* fw1 = (const float*)d_in[7];
  const float* fb1 = (const float*)d_in[8];
  const float* fw2 = (const float*)d_in[9];
  const float* fb2 = (const float*)d_in[10];
  const float* z   = (const float*)d_in[11];

  float* ws = (float*)d_ws;
  float* c1 = ws;                  // 1024*32*400
  float* c2 = ws + 13107200;       // 1024*64*81
  float* c3 = ws;                  // reuses dead c1
  float* pw = ws + 13107200;       // 8*1024*256, reuses dead c2
  float* h  = ws + 15204352;       // 1024*256

  // Transposed weights live in d_out (319488 floats >= 81920); fc2 overwrites
  // d_out at the very end, after the last read of wt3 (conv3).
  float* wt2 = (float*)d_out;            // 32768 floats
  float* wt3 = (float*)d_out + 32768;    // 49152 floats

  float* dist = (float*)d_out;
  float* res  = dist + 1024 * 6 * 51;

  wprep_k<<<192, 256, 0, stream>>>(cw2, cw3, wt2, wt3);
  conv1_k<<<1024, 256, 0, stream>>>(x, cw1, cb1, c1);
  conv2_k<<<1024, 320, 0, stream>>>(c1, wt2, cb2, c2);
  conv3_k<<<1024, 256, 0, stream>>>(c2, wt3, cb3, c3);
  fc1a_k<<<dim3(64, 8), 256, 0, stream>>>(c3, fw1, pw);
  fc1b_k<<<1024, 256, 0, stream>>>(pw, fb1, h);
  fc2_k<<<256, 256, 0, stream>>>(h, fw2, fb2, z, dist, res);
}